// Round 14
// baseline (21.501 us; speedup 1.0000x reference)
//
#include <hip/hip_runtime.h>
#include <hip/hip_bf16.h>

// Volterra conv (K=3, orders 1+2) as one fused bf16 MFMA GEMM.
// r14 = r13 (channel-pair K-packing, 7 ksteps/pair, best known 21.06us) + micro:
//   (1) all 24 x-row loads hoisted ahead of the pair loop (latency off the chain),
//   (2) named ping-pong B buffers (no register-copy rotation),
//   (3) paired epilogue: ds b64 reads (2-way bank alias = free) + dwordx2 stores.
// Math: out[b,l,o] = sum_{c,f} A[l,c*54+f]*Wc[f,o]; pair packs 108 slots -> 112
// (7 ksteps of 16).  Feature g: g<9 linear xp[g]; else xp[P]*xp[Q] (1/sqrt(45)
// folded into Bpack).  Flat out = b*262144 + h*4096 + w*64 + o; bias=bias_w[h].
// Structure: grid 256=(b,h), 512 thr = 8 waves, K-split 4 pairs/wave, reg B dbuf,
// permlane half-exchange, HW cvt_pk_bf16, LDS-only 8-way final reduction.

typedef __bf16 bf16x8 __attribute__((ext_vector_type(8)));
typedef float f32x16 __attribute__((ext_vector_type(16)));

#define SCALE_Q 0.14907119849998599f  // 1/sqrt(45)

__device__ __constant__ int g_pairP[45] = {
  0,0,0,0,0,0,0,0,0, 1,1,1,1,1,1,1,1, 2,2,2,2,2,2,2,
  3,3,3,3,3,3, 4,4,4,4,4, 5,5,5,5, 6,6,6, 7,7, 8};
__device__ __constant__ int g_pairQ[45] = {
  0,1,2,3,4,5,6,7,8, 1,2,3,4,5,6,7,8, 2,3,4,5,6,7,8,
  3,4,5,6,7,8, 4,5,6,7,8, 5,6,7,8, 6,7,8, 7,8, 8};

constexpr int cP[45] = {
  0,0,0,0,0,0,0,0,0, 1,1,1,1,1,1,1,1, 2,2,2,2,2,2,2,
  3,3,3,3,3,3, 4,4,4,4,4, 5,5,5,5, 6,6,6, 7,7, 8};
constexpr int cQ[45] = {
  0,1,2,3,4,5,6,7,8, 1,2,3,4,5,6,7,8, 2,3,4,5,6,7,8,
  3,4,5,6,7,8, 4,5,6,7,8, 5,6,7,8, 6,7,8, 7,8, 8};

union AFrag { unsigned int u[4]; bf16x8 v; };
union BFrag { uint4 q; bf16x8 v; };

// HW packed f32->bf16 (RNE), 1 VALU inst per 2 values.
__device__ inline unsigned int pack_bf16x2(float a, float b){
  unsigned int r;
  asm("v_cvt_pk_bf16_f32 %0, %1, %2" : "=v"(r) : "v"(a), "v"(b));
  return r;
}

// half-exchange: U = own k-low dword, V = own k-high dword ->
// o0 = frag word for output rows 0..31, o1 = for rows 32..63.
__device__ inline void half_swap(unsigned int U, unsigned int V,
                                 unsigned int& o0, unsigned int& o1, int lane){
#if __has_builtin(__builtin_amdgcn_permlane32_swap)
  auto rr = __builtin_amdgcn_permlane32_swap(U, V, false, false);
  o0 = rr[0]; o1 = rr[1];
#else
  unsigned int Ux = (unsigned int)__shfl_xor((int)U, 32);
  unsigned int Vx = (unsigned int)__shfl_xor((int)V, 32);
  const bool hi = (lane >= 32);
  o0 = hi ? Vx : U;
  o1 = hi ? V : Ux;
#endif
}

// pair-slot value; F compile-time constant after full unroll
__device__ inline float slotv(int F, const float (&xp0)[9], const float (&xp1)[9]){
  if (F < 54){  int g = F;      return (g < 9) ? xp0[g] : xp0[cP[g-9]] * xp0[cQ[g-9]]; }
  if (F < 108){ int g = F - 54; return (g < 9) ? xp1[g] : xp1[cP[g-9]] * xp1[cQ[g-9]]; }
  return 0.0f;
}

// ---------------- prep: pack weight channel-PAIRS into MFMA B-frag order ----------------
// chunk G in [0,448): pair Pg=G/14, rem=G%14, t=rem>>1 (kstep 0..6), nb=rem&1.
// chunk (8 bf16, lane kh=lane>>5, col=nb*32+(lane&31)) = B[F = t*16+kh*8+j][col]
__global__ __launch_bounds__(256) void volt_pack(const float* __restrict__ W1,
                                                 const float* __restrict__ W2,
                                                 uint4* __restrict__ Bpack){
  int gt   = blockIdx.x * 256 + threadIdx.x;   // 0..28671
  int G    = gt >> 6;
  int lane = gt & 63;
  int Pg   = G / 14;
  int rem  = G - Pg * 14;
  int t    = rem >> 1;
  int nb   = rem & 1;
  int n    = nb * 32 + (lane & 31);
  int kh   = lane >> 5;
  float wv[8];
  #pragma unroll
  for (int j = 0; j < 8; ++j){
    int F = t * 16 + kh * 8 + j;               // 0..111
    float v = 0.0f;
    if (F < 108){
      int c = 2 * Pg + (F >= 54 ? 1 : 0);
      int g = (F >= 54) ? F - 54 : F;
      if (g < 9) v = W1[(c * 9 + g) * 64 + n];
      else {
        int tt = g - 9;
        v = SCALE_Q * W2[(c * 81 + g_pairP[tt] * 9 + g_pairQ[tt]) * 64 + n];
      }
    }
    wv[j] = v;
  }
  uint4 o;
  o.x = pack_bf16x2(wv[0], wv[1]);
  o.y = pack_bf16x2(wv[2], wv[3]);
  o.z = pack_bf16x2(wv[4], wv[5]);
  o.w = pack_bf16x2(wv[6], wv[7]);
  Bpack[(size_t)G * 64 + lane] = o;            // coalesced 16B store
}

// ---------------- main fused kernel ----------------
__global__ __launch_bounds__(512, 2) void volt_main(const float* __restrict__ x,
                                                    const uint4* __restrict__ Bpack,
                                                    const float* __restrict__ bias_w,
                                                    float* __restrict__ out){
  __shared__ float red[8 * 4096];              // 128 KB: per-wave partial 64x64 tiles
  const int tid  = threadIdx.x;
  const int lane = tid & 63;
  const int kv   = tid >> 6;                   // wave 0..7, pairs kv*4..kv*4+3
  const int b    = blockIdx.x >> 6;
  const int h0   = blockIdx.x & 63;

  const int hm = (h0 > 0)  ? h0 - 1 : 0;       // clamped; masked in build
  const int hp = (h0 < 63) ? h0 + 1 : 63;
  const float* xw   = x + ((size_t)(b * 64 + kv * 8)) * 4096;
  const uint4* bsrc = Bpack + (size_t)(kv * 4) * 896 + lane;   // 14 chunks/pair

  f32x16 acc00{}, acc01{}, acc10{}, acc11{};   // [row-half][col-half]

  auto loadB = [&](int pp, BFrag (&B)[14]){
    const uint4* s = bsrc + (size_t)pp * 896;
    #pragma unroll
    for (int u = 0; u < 14; ++u) B[u].q = s[u * 64];
  };

  auto buildXp = [&](const float (&cx)[3], float (&xp)[9]){
    #pragma unroll
    for (int dh = 0; dh < 3; ++dh){
      float mid = cx[dh];
      if (dh == 0 && h0 == 0)  mid = 0.f;      // wave-uniform row clamp
      if (dh == 2 && h0 == 63) mid = 0.f;
      float lf = __shfl(mid, lane - 1);
      float rt = __shfl(mid, lane + 1);
      xp[dh * 3 + 0] = (lane == 0)  ? 0.f : lf;
      xp[dh * 3 + 1] = mid;
      xp[dh * 3 + 2] = (lane == 63) ? 0.f : rt;
    }
  };

  // one PAIR: feature build + 7 ksteps x 4 MFMAs
  auto compute = [&](const float (&cx0)[3], const float (&cx1)[3], const BFrag (&Bf)[14]){
    float xp0[9], xp1[9];
    buildXp(cx0, xp0);
    buildXp(cx1, xp1);

    __builtin_amdgcn_s_setprio(1);
    #pragma unroll
    for (int t = 0; t < 7; ++t){
      unsigned int dl[8];                      // kh0: slots t*16+0..7; kh1: +8..15
      #pragma unroll
      for (int j = 0; j < 4; ++j){
        const int F0 = t * 16 + 2 * j;         // compile-time after unroll
        dl[j]     = pack_bf16x2(slotv(F0,     xp0, xp1), slotv(F0 + 1, xp0, xp1));
        dl[4 + j] = pack_bf16x2(slotv(F0 + 8, xp0, xp1), slotv(F0 + 9, xp0, xp1));
      }
      AFrag a0, a1;
      #pragma unroll
      for (int j = 0; j < 4; ++j){
        half_swap(dl[j], dl[4 + j], a0.u[j], a1.u[j], lane);
      }
      acc00 = __builtin_amdgcn_mfma_f32_32x32x16_bf16(a0.v, Bf[t*2+0].v, acc00, 0, 0, 0);
      acc01 = __builtin_amdgcn_mfma_f32_32x32x16_bf16(a0.v, Bf[t*2+1].v, acc01, 0, 0, 0);
      acc10 = __builtin_amdgcn_mfma_f32_32x32x16_bf16(a1.v, Bf[t*2+0].v, acc10, 0, 0, 0);
      acc11 = __builtin_amdgcn_mfma_f32_32x32x16_bf16(a1.v, Bf[t*2+1].v, acc11, 0, 0, 0);
    }
    __builtin_amdgcn_s_setprio(0);
  };

  // ---- hoisted x rows: all 8 channels x 3 rows up-front (statically indexed) ----
  BFrag bufA[14], bufB[14];
  loadB(0, bufA);
  float xr[8][3];
  #pragma unroll
  for (int c = 0; c < 8; ++c){
    const float* xc = xw + (size_t)c * 4096;
    xr[c][0] = xc[hm * 64 + lane];
    xr[c][1] = xc[h0 * 64 + lane];
    xr[c][2] = xc[hp * 64 + lane];
  }
  loadB(1, bufB);

  // ---- named ping-pong pair loop (no buffer copies) ----
  compute(xr[0], xr[1], bufA);
  loadB(2, bufA);
  compute(xr[2], xr[3], bufB);
  loadB(3, bufB);
  compute(xr[4], xr[5], bufA);
  compute(xr[6], xr[7], bufB);

  // ---- cross-wave K reduction via LDS ----
  {
    const int colbase = lane & 31;
    const int rowadd  = 4 * (lane >> 5);
    #pragma unroll
    for (int r = 0; r < 16; ++r){
      int rl = (r & 3) + 8 * (r >> 2) + rowadd;              // 32x32 C/D layout
      red[kv * 4096 + (rl)      * 64 + colbase     ] = acc00[r];
      red[kv * 4096 + (rl)      * 64 + colbase + 32] = acc01[r];
      red[kv * 4096 + (rl + 32) * 64 + colbase     ] = acc10[r];
      red[kv * 4096 + (rl + 32) * 64 + colbase + 32] = acc11[r];
    }
  }
  __syncthreads();
  const float bias = bias_w[h0];
  float* outp = out + (size_t)b * 262144 + (size_t)h0 * 4096;
  #pragma unroll
  for (int j = 0; j < 4; ++j){
    int oidx = j * 1024 + tid * 2;             // px*64 + o, pairs; coalesced 8B/lane
    float vx = bias, vy = bias;
    #pragma unroll
    for (int kvv = 0; kvv < 8; ++kvv){
      const float2 t2 = *reinterpret_cast<const float2*>(&red[kvv * 4096 + oidx]);
      vx += t2.x; vy += t2.y;
    }
    float2 o2; o2.x = vx; o2.y = vy;
    *reinterpret_cast<float2*>(&outp[oidx]) = o2;
  }
}

extern "C" void kernel_launch(void* const* d_in, const int* in_sizes, int n_in,
                              void* d_out, int out_size, void* d_ws, size_t ws_size,
                              hipStream_t stream){
  const float* x      = (const float*)d_in[0];
  const float* W1     = (const float*)d_in[1];
  const float* W2     = (const float*)d_in[2];
  const float* bias_w = (const float*)d_in[3];
  float* out = (float*)d_out;
  uint4* Bpack = (uint4*)d_ws;                 // 448 KB

  volt_pack<<<112, 256, 0, stream>>>(W1, W2, Bpack);
  volt_main<<<256, 512, 0, stream>>>(x, (const uint4*)d_ws, bias_w, out);
}